// Round 8
// baseline (650.573 us; speedup 1.0000x reference)
//
#include <hip/hip_runtime.h>

// ---------------------------------------------------------------------------
// QuantSelfAttention on MI355X (gfx950).  B=4, L=1024, C=1024, H=16, D=64.
// Inputs f32, output f32.  Numerics (validated rounds 4/6/7, absmax 1.89e-3):
//   - qkv GEMM: fp16x2-split 3-pass MFMA + per-128-K-slab f64 accumulation
//   - q/k as int8 + per-32-group f64 scale; scores = exact int dots, f64 rescale
//   - softmax + round(a*255) in f64;  AV + proj GEMM post-cliff (f32/bf16)
// Round 8: attn LDS staging was pure overhead (zero reuse per block) and its
// writes were 8-way bank-conflicted (SQ_LDS_BANK_CONFLICT 2.5e7, matched by
// arithmetic).  New k layout kT4[bh][jq][m][w] makes the per-lane k read one
// coalesced global_load_dwordx4 (lane-stride 16B); scales/abias already
// coalesced.  LDS reduced to the 8KB packed nonzero list; one barrier.
// sd values / softmax order / nonzero set / AV order identical to round 7.
//
// ws byte layout (63.2 MB):
//   0         qpre   16MB f32   [aliased as ctx (bf16 8MB) after quant]
//   16777216  kpre   16MB f32
//   33554432  vfq    16MB f32
//   50331648  wprojbf 2MB u16
//   52428800  qint   4MB int8
//   56623104  kT4    4MB int32 (64 bh x 4 jq x 1024 m x 4 w)
//   60817408  qs     1MB f64 (131072 groups)
//   61865984  ksT    1MB f64 (64 bh x 2 p x 1024 m)
//   62914560  vs     32KB f64 (4096)
//   62947328  pmax   256KB f32 (65536)
// ---------------------------------------------------------------------------

typedef unsigned short u16;
typedef unsigned int u32;
typedef __attribute__((ext_vector_type(8))) _Float16 half8;  // 8 f16 (4 VGPRs)
typedef __attribute__((ext_vector_type(4))) float f32x4;     // MFMA accumulator

__device__ __forceinline__ u16 f2b(float f) {   // f32 -> bf16 RNE
    u32 i;
    __builtin_memcpy(&i, &f, 4);
    return (u16)((i + 0x7FFFu + ((i >> 16) & 1u)) >> 16);
}

__device__ __forceinline__ void split16(float v, u16& hi, u16& lo) {
    _Float16 h = (_Float16)v;
    _Float16 l = (_Float16)(v - (float)h);
    __builtin_memcpy(&hi, &h, 2);
    __builtin_memcpy(&lo, &l, 2);
}

__device__ __forceinline__ int dot4(int a, int b, int c) {
#if __has_builtin(__builtin_amdgcn_sdot4)
    return __builtin_amdgcn_sdot4(a, b, c, false);
#else
    int r = c;
    r += ((a << 24) >> 24) * ((b << 24) >> 24);
    r += ((a << 16) >> 24) * ((b << 16) >> 24);
    r += ((a << 8) >> 24) * ((b << 8) >> 24);
    r += (a >> 24) * (b >> 24);
    return r;
#endif
}

// --- K0: w_proj f32 -> bf16 --------------------------------------------------
__global__ __launch_bounds__(256) void cvt_bf16w(u16* __restrict__ dst,
                                                 const float* __restrict__ src, int n) {
    int i = (blockIdx.x * 256 + threadIdx.x) * 4;
    if (i + 3 < n) {
        float4 v = *(const float4*)(src + i);
        ushort4 o;
        o.x = f2b(v.x); o.y = f2b(v.y); o.z = f2b(v.z); o.w = f2b(v.w);
        *(ushort4*)(dst + i) = o;
    }
}

// ---------------------------------------------------------------------------
// K1: qkv = x @ w_qkv^T + bias, fp16x2-split 3-pass MFMA, f64 slab accumulate.
// (unchanged from the round-4/6/7 passing version)
// ---------------------------------------------------------------------------
__global__ __launch_bounds__(256) void gemm_qkv3(const float* __restrict__ A,
                                                 const float* __restrict__ Bm,
                                                 const float* __restrict__ qbias,
                                                 const float* __restrict__ vbias,
                                                 float* __restrict__ qws,
                                                 float* __restrict__ kws,
                                                 float* __restrict__ vws) {
    __shared__ u16 Ah[128 * 32], Al[128 * 32], Bh[128 * 32], Bl[128 * 32];
    const int t = threadIdx.x;
    const int lane = t & 63, w = t >> 6;
    const int wm = w >> 1, wn = w & 1;
    const int srow = t >> 2, scol = (t & 3) * 8;
    const int lm = lane & 15, lk = (lane >> 4) * 8;
    const int bm = blockIdx.y, bn = blockIdx.x;

    const float* ap = A + (size_t)(bm * 128 + srow) * 1024 + scol;
    const float* bp = Bm + (size_t)(bn * 128 + srow) * 1024 + scol;

    double dacc[4][4][4];
#pragma unroll
    for (int i = 0; i < 4; i++)
#pragma unroll
        for (int j = 0; j < 4; j++)
#pragma unroll
            for (int r = 0; r < 4; r++) dacc[i][j][r] = 0.0;

    for (int slab = 0; slab < 8; slab++) {
        f32x4 acc[4][4];
#pragma unroll
        for (int i = 0; i < 4; i++)
#pragma unroll
            for (int j = 0; j < 4; j++) acc[i][j] = (f32x4){0.f, 0.f, 0.f, 0.f};

        for (int kc = 0; kc < 4; kc++) {
            const int k0 = slab * 128 + kc * 32;
            float vreg[4][8];
#pragma unroll
            for (int e = 0; e < 4; e++) {
                const float* src = (e < 2) ? (ap + (e & 1) * (size_t)64 * 1024 + k0)
                                           : (bp + (e & 1) * (size_t)64 * 1024 + k0);
                float4 v0 = *(const float4*)(src);
                float4 v1 = *(const float4*)(src + 4);
                vreg[e][0] = v0.x; vreg[e][1] = v0.y; vreg[e][2] = v0.z; vreg[e][3] = v0.w;
                vreg[e][4] = v1.x; vreg[e][5] = v1.y; vreg[e][6] = v1.z; vreg[e][7] = v1.w;
            }
            __syncthreads();
#pragma unroll
            for (int e = 0; e < 4; e++) {
                union { u16 us[8]; uint4 v; } ph, pl;
#pragma unroll
                for (int j = 0; j < 8; j++) split16(vreg[e][j], ph.us[j], pl.us[j]);
                u16* dh = (e < 2) ? Ah : Bh;
                u16* dl = (e < 2) ? Al : Bl;
                int row = srow + (e & 1) * 64;
                *(uint4*)(dh + row * 32 + scol) = ph.v;
                *(uint4*)(dl + row * 32 + scol) = pl.v;
            }
            __syncthreads();

            half8 fah[4], fal[4], fbh[4], fbl[4];
#pragma unroll
            for (int i = 0; i < 4; i++) {
                int ra = (wm * 64 + i * 16 + lm) * 32 + lk;
                int rb = (wn * 64 + i * 16 + lm) * 32 + lk;
                fah[i] = *(const half8*)(Ah + ra);
                fal[i] = *(const half8*)(Al + ra);
                fbh[i] = *(const half8*)(Bh + rb);
                fbl[i] = *(const half8*)(Bl + rb);
            }
#pragma unroll
            for (int mi = 0; mi < 4; mi++)
#pragma unroll
                for (int ni = 0; ni < 4; ni++) {
                    acc[mi][ni] = __builtin_amdgcn_mfma_f32_16x16x32_f16(
                        fal[mi], fbh[ni], acc[mi][ni], 0, 0, 0);
                    acc[mi][ni] = __builtin_amdgcn_mfma_f32_16x16x32_f16(
                        fah[mi], fbl[ni], acc[mi][ni], 0, 0, 0);
                    acc[mi][ni] = __builtin_amdgcn_mfma_f32_16x16x32_f16(
                        fah[mi], fbh[ni], acc[mi][ni], 0, 0, 0);
                }
        }
#pragma unroll
        for (int i = 0; i < 4; i++)
#pragma unroll
            for (int j = 0; j < 4; j++)
#pragma unroll
                for (int r = 0; r < 4; r++) dacc[i][j][r] += (double)acc[i][j][r];
    }

    const int rbase = bm * 128 + wm * 64 + (lane >> 4) * 4;
    const int cbase = bn * 128 + wn * 64 + lm;
#pragma unroll
    for (int mi = 0; mi < 4; mi++)
#pragma unroll
        for (int ni = 0; ni < 4; ni++) {
            int col = cbase + ni * 16;
            int sel = col >> 10, cc = col & 1023;
            double bias = (sel == 0) ? (double)qbias[cc]
                        : ((sel == 2) ? (double)vbias[cc] : 0.0);
            float* dst = (sel == 0) ? qws : ((sel == 1) ? kws : vws);
#pragma unroll
            for (int r = 0; r < 4; r++) {
                int row = rbase + mi * 16 + r;
                dst[(size_t)row * 1024 + cc] = (float)(dacc[mi][ni][r] + bias);
            }
        }
}

// --- K2a: per-32-group quant of q -> int8 (row-major) + f64 scale ------------
__global__ __launch_bounds__(256) void quant_qk(const float* __restrict__ pre,
                                                signed char* __restrict__ qout,
                                                double* __restrict__ sout) {
    size_t g = (size_t)blockIdx.x * 256 + threadIdx.x;   // 131072 groups
    const float* p = pre + g * 32;
    float v[32];
    float amax = 0.f;
#pragma unroll
    for (int i = 0; i < 8; i++) {
        float4 q4 = ((const float4*)p)[i];
        v[i * 4 + 0] = q4.x; v[i * 4 + 1] = q4.y; v[i * 4 + 2] = q4.z; v[i * 4 + 3] = q4.w;
        amax = fmaxf(amax, fmaxf(fmaxf(fabsf(q4.x), fabsf(q4.y)),
                                 fmaxf(fabsf(q4.z), fabsf(q4.w))));
    }
    double s = fmax((double)amax / 127.0, 1e-8);
    sout[g] = s;
    int pk[8];
#pragma unroll
    for (int i = 0; i < 8; i++) {
        int b0 = (int)fmin(fmax(rint((double)v[i * 4 + 0] / s), -128.0), 127.0);
        int b1 = (int)fmin(fmax(rint((double)v[i * 4 + 1] / s), -128.0), 127.0);
        int b2 = (int)fmin(fmax(rint((double)v[i * 4 + 2] / s), -128.0), 127.0);
        int b3 = (int)fmin(fmax(rint((double)v[i * 4 + 3] / s), -128.0), 127.0);
        pk[i] = (b0 & 255) | ((b1 & 255) << 8) | ((b2 & 255) << 16) | ((b3 & 255) << 24);
    }
    int4* d = (int4*)(qout + g * 32);
    d[0] = make_int4(pk[0], pk[1], pk[2], pk[3]);
    d[1] = make_int4(pk[4], pk[5], pk[6], pk[7]);
}

// --- K2b: per-32-group quant of k -> kT4[bh][jq][m][w] int32 layout ----------
// jq = dword-quad of the 64B head-row; attn reads one int4 per (jq, m):
// lane-stride 16B -> coalesced global_load_dwordx4.  Same math as quant_qk.
__global__ __launch_bounds__(256) void quant_k(const float* __restrict__ pre,
                                               int* __restrict__ kT,
                                               double* __restrict__ ksT) {
    size_t g = (size_t)blockIdx.x * 256 + threadIdx.x;   // 131072 groups
    const float* p = pre + g * 32;
    float v[32];
    float amax = 0.f;
#pragma unroll
    for (int i = 0; i < 8; i++) {
        float4 q4 = ((const float4*)p)[i];
        v[i * 4 + 0] = q4.x; v[i * 4 + 1] = q4.y; v[i * 4 + 2] = q4.z; v[i * 4 + 3] = q4.w;
        amax = fmaxf(amax, fmaxf(fmaxf(fabsf(q4.x), fabsf(q4.y)),
                                 fmaxf(fabsf(q4.z), fabsf(q4.w))));
    }
    double s = fmax((double)amax / 127.0, 1e-8);
    int pk[8];
#pragma unroll
    for (int i = 0; i < 8; i++) {
        int b0 = (int)fmin(fmax(rint((double)v[i * 4 + 0] / s), -128.0), 127.0);
        int b1 = (int)fmin(fmax(rint((double)v[i * 4 + 1] / s), -128.0), 127.0);
        int b2 = (int)fmin(fmax(rint((double)v[i * 4 + 2] / s), -128.0), 127.0);
        int b3 = (int)fmin(fmax(rint((double)v[i * 4 + 3] / s), -128.0), 127.0);
        pk[i] = (b0 & 255) | ((b1 & 255) << 8) | ((b2 & 255) << 16) | ((b3 & 255) << 24);
    }
    const int m = (int)((g >> 5) & 1023);
    const int b = (int)(g >> 15);
    const int sub = (int)(g & 31);
    const int h = sub >> 1, pp = sub & 1;
    const int bh = b * 16 + h;
    // group covers dwords j = pp*8 + i (i<8); jq = j>>2 = pp*2 + (i>>2), w = i&3
    int* dst = kT + (((size_t)bh * 4 + pp * 2) * 1024 + m) * 4;
#pragma unroll
    for (int i = 0; i < 8; i++) dst[(i >> 2) * 4096 + (i & 3)] = pk[i];
    ksT[((size_t)bh * 2 + pp) * 1024 + m] = s;
}

// --- K3a: partial max|v| over 64-row L-chunks --------------------------------
__global__ __launch_bounds__(256) void vmax_part(const float* __restrict__ vws,
                                                 float* __restrict__ pmax) {
    const int lc = blockIdx.x, b = blockIdx.y, t = threadIdx.x;
#pragma unroll
    for (int j = 0; j < 4; j++) {
        int cc = t + j * 256;
        float mx = 0.f;
        for (int l = 0; l < 64; l++)
            mx = fmaxf(mx, fabsf(vws[((size_t)(b * 1024 + lc * 64 + l)) * 1024 + cc]));
        pmax[(size_t)(b * 16 + lc) * 1024 + cc] = mx;
    }
}

// --- K3b: reduce -> vs[b*1024+cc] = max(amax/127, eps) in f64 ----------------
__global__ __launch_bounds__(256) void vmax_final(const float* __restrict__ pmax,
                                                  double* __restrict__ vs) {
    int id = blockIdx.x * 256 + threadIdx.x;   // 4096
    int b = id >> 10, cc = id & 1023;
    float mx = 0.f;
#pragma unroll
    for (int p = 0; p < 16; p++)
        mx = fmaxf(mx, pmax[(size_t)(b * 16 + p) * 1024 + cc]);
    vs[id] = fmax((double)mx / 127.0, 1e-8);
}

// --- K3c: fake-quant v in place (f64 decisions, f32 store) -------------------
__global__ __launch_bounds__(256) void vquant(float* __restrict__ vws,
                                              const double* __restrict__ vs) {
    size_t e = ((size_t)blockIdx.x * 256 + threadIdx.x) * 4;
    int b = (int)(e >> 20), cc = (int)(e & 1023);
    float4 v = *(const float4*)(vws + e);
    double s0 = vs[b * 1024 + cc], s1 = vs[b * 1024 + cc + 1];
    double s2 = vs[b * 1024 + cc + 2], s3 = vs[b * 1024 + cc + 3];
    float4 o;
    o.x = (float)(fmin(fmax(rint((double)v.x / s0), -128.0), 127.0) * s0);
    o.y = (float)(fmin(fmax(rint((double)v.y / s1), -128.0), 127.0) * s1);
    o.z = (float)(fmin(fmax(rint((double)v.z / s2), -128.0), 127.0) * s2);
    o.w = (float)(fmin(fmax(rint((double)v.w / s3), -128.0), 127.0) * s3);
    *(float4*)(vws + e) = o;
}

// ---------------------------------------------------------------------------
// K4: attention, one wave per query row, NO k/scale staging.
// Block = 4 waves = 4 rows of one (b,h).  Lane l holds scores m = it*64+l:
// k read = 4 coalesced global dwordx4 per it (kT4 layout), scales/abias
// coalesced global.  LDS = only the 8KB packed nonzero list; one barrier.
// sd values / softmax order / nonzero set / AV order identical to round 7.
// ---------------------------------------------------------------------------
__global__ __launch_bounds__(256) void attn(const signed char* __restrict__ qint,
                                            const int* __restrict__ kT4,
                                            const double* __restrict__ qs,
                                            const double* __restrict__ ksT,
                                            const float* __restrict__ vfq,
                                            const float* __restrict__ abias,
                                            u16* __restrict__ ctx) {
    __shared__ u32 packed[4][512];   // 8 KB: (n<<16)|m nonzero list per wave
    const int t = threadIdx.x;
    const int wv = t >> 6, lane = t & 63;
    const int qt = blockIdx.x, h = blockIdx.y, b = blockIdx.z;
    const int row = qt * 4 + wv;
    const size_t qrow = (size_t)(b * 1024 + row);
    const int bh = b * 16 + h;

    // q row: 64 int8 = 16 ints (same 64B for all lanes -> cache broadcast)
    const int* qv = (const int*)(qint + qrow * 1024 + h * 64);
    int qd[16];
#pragma unroll
    for (int j = 0; j < 4; j++) {
        int4 tmp = ((const int4*)qv)[j];
        qd[j * 4 + 0] = tmp.x; qd[j * 4 + 1] = tmp.y;
        qd[j * 4 + 2] = tmp.z; qd[j * 4 + 3] = tmp.w;
    }
    const double sq0 = qs[qrow * 32 + 2 * h], sq1 = qs[qrow * 32 + 2 * h + 1];
    const int4* kB = (const int4*)kT4 + (size_t)bh * 4096;   // 4 jq x 1024 m
    const double* ks0g = ksT + (size_t)(bh * 2) * 1024;
    const double* ks1g = ksT + (size_t)(bh * 2 + 1) * 1024;
    const float* ab = abias + (size_t)row * 1024;

    double sd[16];
#pragma unroll
    for (int it = 0; it < 16; it++) {
        const int m = it * 64 + lane;
        int4 k0 = kB[m];
        int4 k1 = kB[1024 + m];
        int4 k2 = kB[2048 + m];
        int4 k3 = kB[3072 + m];
        int I0 = 0, I1 = 0;
        I0 = dot4(qd[0], k0.x, I0);  I0 = dot4(qd[1], k0.y, I0);
        I0 = dot4(qd[2], k0.z, I0);  I0 = dot4(qd[3], k0.w, I0);
        I0 = dot4(qd[4], k1.x, I0);  I0 = dot4(qd[5], k1.y, I0);
        I0 = dot4(qd[6], k1.z, I0);  I0 = dot4(qd[7], k1.w, I0);
        I1 = dot4(qd[8], k2.x, I1);  I1 = dot4(qd[9], k2.y, I1);
        I1 = dot4(qd[10], k2.z, I1); I1 = dot4(qd[11], k2.w, I1);
        I1 = dot4(qd[12], k3.x, I1); I1 = dot4(qd[13], k3.y, I1);
        I1 = dot4(qd[14], k3.z, I1); I1 = dot4(qd[15], k3.w, I1);
        sd[it] = 0.125 * (sq0 * ks0g[m] * (double)I0
                        + sq1 * ks1g[m] * (double)I1)
               + (double)ab[m];
    }

    // softmax (f64): 16 local + 6-step wave shuffle (identical to rounds 6/7)
    double mx = sd[0];
#pragma unroll
    for (int it = 1; it < 16; it++) mx = fmax(mx, sd[it]);
#pragma unroll
    for (int off = 1; off < 64; off <<= 1) mx = fmax(mx, __shfl_xor(mx, off));
    double sum = 0.0;
#pragma unroll
    for (int it = 0; it < 16; it++) {
        double e = exp(sd[it] - mx);
        sd[it] = e;
        sum += e;
    }
#pragma unroll
    for (int off = 1; off < 64; off <<= 1) sum += __shfl_xor(sum, off);

    // static quant + ballot compaction of nonzeros (ascending m)
    int base = 0;
#pragma unroll
    for (int it = 0; it < 16; it++) {
        double a = sd[it] / sum;
        double nd = fmin(fmax(rint(a * 255.0), 0.0), 255.0);
        int ni = (int)nd;
        unsigned long long mk = __ballot(ni != 0);
        if (ni != 0) {
            int pos = base + (int)__popcll(mk & ((1ull << lane) - 1ull));
            packed[wv][pos] = ((u32)ni << 16) | (u32)(it * 64 + lane);
        }
        base += (int)__popcll(mk);
    }
    __syncthreads();

    // AV: lane = head dim; iterate compacted list (wave-uniform trip count).
    // a = n/255.0f is a correctly-rounded f32 divide == round 7's value.
    float acc = 0.f;
    const float* vcol = vfq + ((size_t)b * 1024) * 1024 + h * 64 + lane;
    for (int j = 0; j < base; ++j) {
        u32 p = packed[wv][j];
        float a = (float)(p >> 16) / 255.0f;
        acc = fmaf(a, vcol[(size_t)(p & 1023u) * 1024], acc);
    }
    ctx[qrow * 1024 + h * 64 + lane] = f2b(acc);
}

// --- K5: out = ctx @ w_proj^T + b_proj, bf16 MFMA (post-cliff) ---------------
__global__ __launch_bounds__(256) void gemm_proj(const u16* __restrict__ ctx,
                                                 const u16* __restrict__ wproj,
                                                 const float* __restrict__ bproj,
                                                 float* __restrict__ out) {
    typedef __attribute__((ext_vector_type(8))) short short8;
    __shared__ u16 As[128 * 32], Bs[128 * 32];
    f32x4 acc[4][4];
#pragma unroll
    for (int i = 0; i < 4; i++)
#pragma unroll
        for (int j = 0; j < 4; j++) acc[i][j] = (f32x4){0.f, 0.f, 0.f, 0.f};

    const int t = threadIdx.x;
    const int lane = t & 63, w = t >> 6;
    const int wm = w >> 1, wn = w & 1;
    const int srow = t >> 2, scol = (t & 3) * 8;
    const int lm = lane & 15, lk = (lane >> 4) * 8;
    const int bm = blockIdx.y, bn = blockIdx.x;
    const u16* ap = ctx + (size_t)(bm * 128 + srow) * 1024 + scol;
    const u16* bp = wproj + (size_t)(bn * 128 + srow) * 1024 + scol;

    for (int k0 = 0; k0 < 1024; k0 += 32) {
        uint4 a0 = *(const uint4*)(ap + k0);
        uint4 a1 = *(const uint4*)(ap + (size_t)64 * 1024 + k0);
        uint4 b0 = *(const uint4*)(bp + k0);
        uint4 b1 = *(const uint4*)(bp + (size_t)64 * 1024 + k0);
        __syncthreads();
        *(uint4*)(As + srow * 32 + scol) = a0;
        *(uint4*)(As + (srow + 64) * 32 + scol) = a1;
        *(uint4*)(Bs + srow * 32 + scol) = b0;
        *(uint4*)(Bs + (srow + 64) * 32 + scol) = b1;
        __syncthreads();
        short8 af[4], bfr[4];
#pragma unroll
        for (int i = 0; i < 4; i++) {
            af[i]  = *(const short8*)(As + (wm * 64 + i * 16 + lm) * 32 + lk);
            bfr[i] = *(const short8*)(Bs + (wn * 64 + i * 16 + lm) * 32 + lk);
        }
#pragma unroll
        for (int mi = 0; mi < 4; mi++)
#pragma unroll
            for (int ni = 0; ni < 4; ni++)
                acc[mi][ni] = __builtin_amdgcn_mfma_f32_16x16x32_bf16(
                    af[mi], bfr[ni], acc[mi][ni], 0, 0, 0);
    }

    const int rbase = bm * 128 + wm * 64 + (lane >> 4) * 4;
    const int cbase = bn * 128 + wn * 64 + lm;
#pragma unroll
    for (int mi = 0; mi < 4; mi++)
#pragma unroll
        for (int ni = 0; ni < 4; ni++) {
            int col = cbase + ni * 16;
            float bias = bproj[col];
#pragma unroll
            for (int r = 0; r < 4; r++) {
                int row = rbase + mi * 16 + r;
                out[(size_t)row * 1024 + col] = acc[mi][ni][r] + bias;
            }
        }
}

// ---------------------------------------------------------------------------
extern "C" void kernel_launch(void* const* d_in, const int* in_sizes, int n_in,
                              void* d_out, int out_size, void* d_ws, size_t ws_size,
                              hipStream_t stream) {
    const float* x     = (const float*)d_in[0];
    const float* abias = (const float*)d_in[1];
    const float* wqkv  = (const float*)d_in[2];
    const float* qbias = (const float*)d_in[3];
    const float* vbias = (const float*)d_in[4];
    const float* wproj = (const float*)d_in[5];
    const float* bproj = (const float*)d_in[6];
    float* out = (float*)d_out;

    char* ws = (char*)d_ws;
    float*       qpre    = (float*)(ws + 0);
    float*       kpre    = (float*)(ws + 16777216);
    float*       vfq     = (float*)(ws + 33554432);
    u16*         wprojbf = (u16*)  (ws + 50331648);
    signed char* qint    = (signed char*)(ws + 52428800);
    int*         kT4     = (int*)  (ws + 56623104);
    double*      qs      = (double*)(ws + 60817408);
    double*      ksT     = (double*)(ws + 61865984);
    double*      vs      = (double*)(ws + 62914560);
    float*       pmax    = (float*)(ws + 62947328);
    u16*         ctx     = (u16*)(ws + 0);          // alias qpre (dead after quant)

    cvt_bf16w<<<1024, 256, 0, stream>>>(wprojbf, wproj, 1048576);
    gemm_qkv3<<<dim3(24, 32), 256, 0, stream>>>(x, wqkv, qbias, vbias,
                                                qpre, kpre, vfq);
    quant_qk<<<512, 256, 0, stream>>>(qpre, qint, qs);
    quant_k<<<512, 256, 0, stream>>>(kpre, kT4, ksT);
    vmax_part<<<dim3(16, 4), 256, 0, stream>>>(vfq, pmax);
    vmax_final<<<16, 256, 0, stream>>>(pmax, vs);
    vquant<<<4096, 256, 0, stream>>>(vfq, vs);
    attn<<<dim3(256, 16, 4), 256, 0, stream>>>(qint, kT4, qs, ksT, vfq, abias, ctx);
    gemm_proj<<<dim3(8, 32), 256, 0, stream>>>(ctx, wprojbf, bproj, out);
}

// Round 9
// 584.092 us; speedup vs baseline: 1.1138x; 1.1138x over previous
//
#include <hip/hip_runtime.h>

// ---------------------------------------------------------------------------
// QuantSelfAttention on MI355X (gfx950).  B=4, L=1024, C=1024, H=16, D=64.
// Inputs f32, output f32.  Numerics (validated rounds 4/6/7/8, absmax 1.89e-3):
//   - qkv GEMM: fp16x2-split 3-pass MFMA + per-128-K-slab f64 accumulation
//   - q/k as int8 + per-32-group f64 scale; scores = exact int dots, f64 rescale
//   - softmax + round(a*255) in f64;  AV + proj GEMM post-cliff (f32/bf16)
// Round 9: round-7 LDS-staged attn (cross-wave k reuse, 294us) was right;
// round-8's all-global variant lost 4x reuse (351us).  The round-7 defect was
// only the staging WRITE pattern (64B lane-stride -> 8-way bank conflict,
// 2.5e7 cycles).  Fix: wave w writes LDS rows j=w*4+r contiguously (lane l
// -> cols 4l..4l+3, 16B lane-stride = conflict-free b128), global k stays
// j-major coalesced.  Score reads kTs[j][ml] already conflict-free.
// sd values / softmax order / nonzero set / AV order identical to rounds 7/8.
//
// ws byte layout (63.2 MB):
//   0         qpre   16MB f32   [aliased as ctx (bf16 8MB) after quant]
//   16777216  kpre   16MB f32
//   33554432  vfq    16MB f32
//   50331648  wprojbf 2MB u16
//   52428800  qint   4MB int8
//   56623104  kT     4MB int32 (64 bh x 16 j x 1024 m)
//   60817408  qs     1MB f64 (131072 groups)
//   61865984  ksT    1MB f64 (64 bh x 2 p x 1024 m)
//   62914560  vs     32KB f64 (4096)
//   62947328  pmax   256KB f32 (65536)
// ---------------------------------------------------------------------------

typedef unsigned short u16;
typedef unsigned int u32;
typedef __attribute__((ext_vector_type(8))) _Float16 half8;  // 8 f16 (4 VGPRs)
typedef __attribute__((ext_vector_type(4))) float f32x4;     // MFMA accumulator

__device__ __forceinline__ u16 f2b(float f) {   // f32 -> bf16 RNE
    u32 i;
    __builtin_memcpy(&i, &f, 4);
    return (u16)((i + 0x7FFFu + ((i >> 16) & 1u)) >> 16);
}

__device__ __forceinline__ void split16(float v, u16& hi, u16& lo) {
    _Float16 h = (_Float16)v;
    _Float16 l = (_Float16)(v - (float)h);
    __builtin_memcpy(&hi, &h, 2);
    __builtin_memcpy(&lo, &l, 2);
}

__device__ __forceinline__ int dot4(int a, int b, int c) {
#if __has_builtin(__builtin_amdgcn_sdot4)
    return __builtin_amdgcn_sdot4(a, b, c, false);
#else
    int r = c;
    r += ((a << 24) >> 24) * ((b << 24) >> 24);
    r += ((a << 16) >> 24) * ((b << 16) >> 24);
    r += ((a << 8) >> 24) * ((b << 8) >> 24);
    r += (a >> 24) * (b >> 24);
    return r;
#endif
}

// --- K0: w_proj f32 -> bf16 --------------------------------------------------
__global__ __launch_bounds__(256) void cvt_bf16w(u16* __restrict__ dst,
                                                 const float* __restrict__ src, int n) {
    int i = (blockIdx.x * 256 + threadIdx.x) * 4;
    if (i + 3 < n) {
        float4 v = *(const float4*)(src + i);
        ushort4 o;
        o.x = f2b(v.x); o.y = f2b(v.y); o.z = f2b(v.z); o.w = f2b(v.w);
        *(ushort4*)(dst + i) = o;
    }
}

// ---------------------------------------------------------------------------
// K1: qkv = x @ w_qkv^T + bias, fp16x2-split 3-pass MFMA, f64 slab accumulate.
// (unchanged from the round-4/6/7/8 passing version)
// ---------------------------------------------------------------------------
__global__ __launch_bounds__(256) void gemm_qkv3(const float* __restrict__ A,
                                                 const float* __restrict__ Bm,
                                                 const float* __restrict__ qbias,
                                                 const float* __restrict__ vbias,
                                                 float* __restrict__ qws,
                                                 float* __restrict__ kws,
                                                 float* __restrict__ vws) {
    __shared__ u16 Ah[128 * 32], Al[128 * 32], Bh[128 * 32], Bl[128 * 32];
    const int t = threadIdx.x;
    const int lane = t & 63, w = t >> 6;
    const int wm = w >> 1, wn = w & 1;
    const int srow = t >> 2, scol = (t & 3) * 8;
    const int lm = lane & 15, lk = (lane >> 4) * 8;
    const int bm = blockIdx.y, bn = blockIdx.x;

    const float* ap = A + (size_t)(bm * 128 + srow) * 1024 + scol;
    const float* bp = Bm + (size_t)(bn * 128 + srow) * 1024 + scol;

    double dacc[4][4][4];
#pragma unroll
    for (int i = 0; i < 4; i++)
#pragma unroll
        for (int j = 0; j < 4; j++)
#pragma unroll
            for (int r = 0; r < 4; r++) dacc[i][j][r] = 0.0;

    for (int slab = 0; slab < 8; slab++) {
        f32x4 acc[4][4];
#pragma unroll
        for (int i = 0; i < 4; i++)
#pragma unroll
            for (int j = 0; j < 4; j++) acc[i][j] = (f32x4){0.f, 0.f, 0.f, 0.f};

        for (int kc = 0; kc < 4; kc++) {
            const int k0 = slab * 128 + kc * 32;
            float vreg[4][8];
#pragma unroll
            for (int e = 0; e < 4; e++) {
                const float* src = (e < 2) ? (ap + (e & 1) * (size_t)64 * 1024 + k0)
                                           : (bp + (e & 1) * (size_t)64 * 1024 + k0);
                float4 v0 = *(const float4*)(src);
                float4 v1 = *(const float4*)(src + 4);
                vreg[e][0] = v0.x; vreg[e][1] = v0.y; vreg[e][2] = v0.z; vreg[e][3] = v0.w;
                vreg[e][4] = v1.x; vreg[e][5] = v1.y; vreg[e][6] = v1.z; vreg[e][7] = v1.w;
            }
            __syncthreads();
#pragma unroll
            for (int e = 0; e < 4; e++) {
                union { u16 us[8]; uint4 v; } ph, pl;
#pragma unroll
                for (int j = 0; j < 8; j++) split16(vreg[e][j], ph.us[j], pl.us[j]);
                u16* dh = (e < 2) ? Ah : Bh;
                u16* dl = (e < 2) ? Al : Bl;
                int row = srow + (e & 1) * 64;
                *(uint4*)(dh + row * 32 + scol) = ph.v;
                *(uint4*)(dl + row * 32 + scol) = pl.v;
            }
            __syncthreads();

            half8 fah[4], fal[4], fbh[4], fbl[4];
#pragma unroll
            for (int i = 0; i < 4; i++) {
                int ra = (wm * 64 + i * 16 + lm) * 32 + lk;
                int rb = (wn * 64 + i * 16 + lm) * 32 + lk;
                fah[i] = *(const half8*)(Ah + ra);
                fal[i] = *(const half8*)(Al + ra);
                fbh[i] = *(const half8*)(Bh + rb);
                fbl[i] = *(const half8*)(Bl + rb);
            }
#pragma unroll
            for (int mi = 0; mi < 4; mi++)
#pragma unroll
                for (int ni = 0; ni < 4; ni++) {
                    acc[mi][ni] = __builtin_amdgcn_mfma_f32_16x16x32_f16(
                        fal[mi], fbh[ni], acc[mi][ni], 0, 0, 0);
                    acc[mi][ni] = __builtin_amdgcn_mfma_f32_16x16x32_f16(
                        fah[mi], fbl[ni], acc[mi][ni], 0, 0, 0);
                    acc[mi][ni] = __builtin_amdgcn_mfma_f32_16x16x32_f16(
                        fah[mi], fbh[ni], acc[mi][ni], 0, 0, 0);
                }
        }
#pragma unroll
        for (int i = 0; i < 4; i++)
#pragma unroll
            for (int j = 0; j < 4; j++)
#pragma unroll
                for (int r = 0; r < 4; r++) dacc[i][j][r] += (double)acc[i][j][r];
    }

    const int rbase = bm * 128 + wm * 64 + (lane >> 4) * 4;
    const int cbase = bn * 128 + wn * 64 + lm;
#pragma unroll
    for (int mi = 0; mi < 4; mi++)
#pragma unroll
        for (int ni = 0; ni < 4; ni++) {
            int col = cbase + ni * 16;
            int sel = col >> 10, cc = col & 1023;
            double bias = (sel == 0) ? (double)qbias[cc]
                        : ((sel == 2) ? (double)vbias[cc] : 0.0);
            float* dst = (sel == 0) ? qws : ((sel == 1) ? kws : vws);
#pragma unroll
            for (int r = 0; r < 4; r++) {
                int row = rbase + mi * 16 + r;
                dst[(size_t)row * 1024 + cc] = (float)(dacc[mi][ni][r] + bias);
            }
        }
}

// --- K2a: per-32-group quant of q -> int8 (row-major) + f64 scale ------------
__global__ __launch_bounds__(256) void quant_qk(const float* __restrict__ pre,
                                                signed char* __restrict__ qout,
                                                double* __restrict__ sout) {
    size_t g = (size_t)blockIdx.x * 256 + threadIdx.x;   // 131072 groups
    const float* p = pre + g * 32;
    float v[32];
    float amax = 0.f;
#pragma unroll
    for (int i = 0; i < 8; i++) {
        float4 q4 = ((const float4*)p)[i];
        v[i * 4 + 0] = q4.x; v[i * 4 + 1] = q4.y; v[i * 4 + 2] = q4.z; v[i * 4 + 3] = q4.w;
        amax = fmaxf(amax, fmaxf(fmaxf(fabsf(q4.x), fabsf(q4.y)),
                                 fmaxf(fabsf(q4.z), fabsf(q4.w))));
    }
    double s = fmax((double)amax / 127.0, 1e-8);
    sout[g] = s;
    int pk[8];
#pragma unroll
    for (int i = 0; i < 8; i++) {
        int b0 = (int)fmin(fmax(rint((double)v[i * 4 + 0] / s), -128.0), 127.0);
        int b1 = (int)fmin(fmax(rint((double)v[i * 4 + 1] / s), -128.0), 127.0);
        int b2 = (int)fmin(fmax(rint((double)v[i * 4 + 2] / s), -128.0), 127.0);
        int b3 = (int)fmin(fmax(rint((double)v[i * 4 + 3] / s), -128.0), 127.0);
        pk[i] = (b0 & 255) | ((b1 & 255) << 8) | ((b2 & 255) << 16) | ((b3 & 255) << 24);
    }
    int4* d = (int4*)(qout + g * 32);
    d[0] = make_int4(pk[0], pk[1], pk[2], pk[3]);
    d[1] = make_int4(pk[4], pk[5], pk[6], pk[7]);
}

// --- K2b: per-32-group quant of k -> TRANSPOSED j-major layout ---------------
// kT[bh][j][m] (j = dword 0..15 of the 64B head-row), ksT[bh][p][m].
// Scatter writes once (~2us) so attn's staging reads are coalesced.
__global__ __launch_bounds__(256) void quant_k(const float* __restrict__ pre,
                                               int* __restrict__ kT,
                                               double* __restrict__ ksT) {
    size_t g = (size_t)blockIdx.x * 256 + threadIdx.x;   // 131072 groups
    const float* p = pre + g * 32;
    float v[32];
    float amax = 0.f;
#pragma unroll
    for (int i = 0; i < 8; i++) {
        float4 q4 = ((const float4*)p)[i];
        v[i * 4 + 0] = q4.x; v[i * 4 + 1] = q4.y; v[i * 4 + 2] = q4.z; v[i * 4 + 3] = q4.w;
        amax = fmaxf(amax, fmaxf(fmaxf(fabsf(q4.x), fabsf(q4.y)),
                                 fmaxf(fabsf(q4.z), fabsf(q4.w))));
    }
    double s = fmax((double)amax / 127.0, 1e-8);
    int pk[8];
#pragma unroll
    for (int i = 0; i < 8; i++) {
        int b0 = (int)fmin(fmax(rint((double)v[i * 4 + 0] / s), -128.0), 127.0);
        int b1 = (int)fmin(fmax(rint((double)v[i * 4 + 1] / s), -128.0), 127.0);
        int b2 = (int)fmin(fmax(rint((double)v[i * 4 + 2] / s), -128.0), 127.0);
        int b3 = (int)fmin(fmax(rint((double)v[i * 4 + 3] / s), -128.0), 127.0);
        pk[i] = (b0 & 255) | ((b1 & 255) << 8) | ((b2 & 255) << 16) | ((b3 & 255) << 24);
    }
    const int m = (int)((g >> 5) & 1023);
    const int b = (int)(g >> 15);
    const int sub = (int)(g & 31);
    const int h = sub >> 1, pp = sub & 1;
    const int bh = b * 16 + h;
    int* dst = kT + ((size_t)bh * 16 + pp * 8) * 1024 + m;
#pragma unroll
    for (int i = 0; i < 8; i++) dst[i * 1024] = pk[i];
    ksT[((size_t)bh * 2 + pp) * 1024 + m] = s;
}

// --- K3a: partial max|v| over 64-row L-chunks --------------------------------
__global__ __launch_bounds__(256) void vmax_part(const float* __restrict__ vws,
                                                 float* __restrict__ pmax) {
    const int lc = blockIdx.x, b = blockIdx.y, t = threadIdx.x;
#pragma unroll
    for (int j = 0; j < 4; j++) {
        int cc = t + j * 256;
        float mx = 0.f;
        for (int l = 0; l < 64; l++)
            mx = fmaxf(mx, fabsf(vws[((size_t)(b * 1024 + lc * 64 + l)) * 1024 + cc]));
        pmax[(size_t)(b * 16 + lc) * 1024 + cc] = mx;
    }
}

// --- K3b: reduce -> vs[b*1024+cc] = max(amax/127, eps) in f64 ----------------
__global__ __launch_bounds__(256) void vmax_final(const float* __restrict__ pmax,
                                                  double* __restrict__ vs) {
    int id = blockIdx.x * 256 + threadIdx.x;   // 4096
    int b = id >> 10, cc = id & 1023;
    float mx = 0.f;
#pragma unroll
    for (int p = 0; p < 16; p++)
        mx = fmaxf(mx, pmax[(size_t)(b * 16 + p) * 1024 + cc]);
    vs[id] = fmax((double)mx / 127.0, 1e-8);
}

// --- K3c: fake-quant v in place (f64 decisions, f32 store) -------------------
__global__ __launch_bounds__(256) void vquant(float* __restrict__ vws,
                                              const double* __restrict__ vs) {
    size_t e = ((size_t)blockIdx.x * 256 + threadIdx.x) * 4;
    int b = (int)(e >> 20), cc = (int)(e & 1023);
    float4 v = *(const float4*)(vws + e);
    double s0 = vs[b * 1024 + cc], s1 = vs[b * 1024 + cc + 1];
    double s2 = vs[b * 1024 + cc + 2], s3 = vs[b * 1024 + cc + 3];
    float4 o;
    o.x = (float)(fmin(fmax(rint((double)v.x / s0), -128.0), 127.0) * s0);
    o.y = (float)(fmin(fmax(rint((double)v.y / s1), -128.0), 127.0) * s1);
    o.z = (float)(fmin(fmax(rint((double)v.z / s2), -128.0), 127.0) * s2);
    o.w = (float)(fmin(fmax(rint((double)v.w / s3), -128.0), 127.0) * s3);
    *(float4*)(vws + e) = o;
}

// ---------------------------------------------------------------------------
// K4: attention, one wave per query row, LDS-staged k with conflict-free
// staging.  Block = 4 waves = 4 rows of one (b,h).  4 chunks of 256 m:
// wave w writes LDS rows j=w*4+r CONTIGUOUSLY (lane l -> cols 4l..4l+3,
// 16B lane-stride b128 = conflict-free), sourced from j-major global kT
// (coalesced dwordx4).  Score reads kTs[j][ml] lane-stride 4B (2/bank, free).
// sd values / softmax order / nonzero set / AV order identical to rounds 7/8.
// ---------------------------------------------------------------------------
__global__ __launch_bounds__(256) void attn(const signed char* __restrict__ qint,
                                            const int* __restrict__ kT,
                                            const double* __restrict__ qs,
                                            const double* __restrict__ ksT,
                                            const float* __restrict__ vfq,
                                            const float* __restrict__ abias,
                                            u16* __restrict__ ctx) {
    __shared__ int    kTs[16][256];        // 16 KB
    __shared__ double ks0s[256], ks1s[256];//  4 KB
    __shared__ u32    packed[4][512];      //  8 KB: (n<<16)|m nonzero list
    const int t = threadIdx.x;
    const int wv = t >> 6, lane = t & 63;
    const int qt = blockIdx.x, h = blockIdx.y, b = blockIdx.z;
    const int row = qt * 4 + wv;
    const size_t qrow = (size_t)(b * 1024 + row);
    const int bh = b * 16 + h;

    // q row: 64 int8 = 16 ints (same 64B for all lanes -> cache broadcast)
    const int* qv = (const int*)(qint + qrow * 1024 + h * 64);
    int qd[16];
#pragma unroll
    for (int j = 0; j < 4; j++) {
        int4 tmp = ((const int4*)qv)[j];
        qd[j * 4 + 0] = tmp.x; qd[j * 4 + 1] = tmp.y;
        qd[j * 4 + 2] = tmp.z; qd[j * 4 + 3] = tmp.w;
    }
    const double sq0 = qs[qrow * 32 + 2 * h], sq1 = qs[qrow * 32 + 2 * h + 1];
    const int* kTg = kT + (size_t)bh * 16384;
    const double* ks0g = ksT + (size_t)(bh * 2) * 1024;
    const double* ks1g = ksT + (size_t)(bh * 2 + 1) * 1024;
    const float* ab = abias + (size_t)row * 1024;

    double sd[16];
    for (int c = 0; c < 4; c++) {
        if (c) __syncthreads();             // protect previous chunk's reads
        // staging: wave w fills rows j=w*4+r, lane l -> cols 4l..4l+3
#pragma unroll
        for (int r = 0; r < 4; r++) {
            const int j = wv * 4 + r;
            int4 val = *(const int4*)(kTg + (size_t)j * 1024 + c * 256 + 4 * lane);
            *(int4*)(&kTs[j][4 * lane]) = val;
        }
        ks0s[t] = ks0g[c * 256 + t];
        ks1s[t] = ks1g[c * 256 + t];
        __syncthreads();
#pragma unroll
        for (int s = 0; s < 4; s++) {
            const int ml = s * 64 + lane;
            int I0 = 0, I1 = 0;
#pragma unroll
            for (int j = 0; j < 8; j++)  I0 = dot4(qd[j], kTs[j][ml], I0);
#pragma unroll
            for (int j = 8; j < 16; j++) I1 = dot4(qd[j], kTs[j][ml], I1);
            sd[c * 4 + s] = 0.125 * (sq0 * ks0s[ml] * (double)I0
                                   + sq1 * ks1s[ml] * (double)I1)
                          + (double)ab[c * 256 + ml];
        }
    }

    // softmax (f64): 16 local + 6-step wave shuffle (identical to rounds 6-8)
    double mx = sd[0];
#pragma unroll
    for (int it = 1; it < 16; it++) mx = fmax(mx, sd[it]);
#pragma unroll
    for (int off = 1; off < 64; off <<= 1) mx = fmax(mx, __shfl_xor(mx, off));
    double sum = 0.0;
#pragma unroll
    for (int it = 0; it < 16; it++) {
        double e = exp(sd[it] - mx);
        sd[it] = e;
        sum += e;
    }
#pragma unroll
    for (int off = 1; off < 64; off <<= 1) sum += __shfl_xor(sum, off);

    // static quant + ballot compaction of nonzeros (ascending m)
    int base = 0;
#pragma unroll
    for (int it = 0; it < 16; it++) {
        double a = sd[it] / sum;
        double nd = fmin(fmax(rint(a * 255.0), 0.0), 255.0);
        int ni = (int)nd;
        unsigned long long mk = __ballot(ni != 0);
        if (ni != 0) {
            int pos = base + (int)__popcll(mk & ((1ull << lane) - 1ull));
            packed[wv][pos] = ((u32)ni << 16) | (u32)(it * 64 + lane);
        }
        base += (int)__popcll(mk);
    }
    __syncthreads();

    // AV: lane = head dim; iterate compacted list (wave-uniform trip count).
    // a = n/255.0f is a correctly-rounded f32 divide == rounds 7/8 value.
    float acc = 0.f;
    const float* vcol = vfq + ((size_t)b * 1024) * 1024 + h * 64 + lane;
    for (int j = 0; j < base; ++j) {
        u32 p = packed[wv][j];
        float a = (float)(p >> 16) / 255.0f;
        acc = fmaf(a, vcol[(size_t)(p & 1023u) * 1024], acc);
    }
    ctx[qrow * 1024 + h * 64 + lane] = f2b(acc);
}

// --- K5: out = ctx @ w_proj^T + b_proj, bf16 MFMA (post-cliff) ---------------
__global__ __launch_bounds__(256) void gemm_proj(const u16* __restrict__ ctx,
                                                 const u16* __restrict__ wproj,
                                                 const float* __restrict__ bproj,
                                                 float* __restrict__ out) {
    typedef __attribute__((ext_vector_type(8))) short short8;
    __shared__ u16 As[128 * 32], Bs[128 * 32];
    f32x4 acc[4][4];
#pragma unroll
    for (int i = 0; i < 4; i++)
#pragma unroll
        for (int j = 0; j < 4; j++) acc[i][j] = (f32x4){0.f, 0.f, 0.f, 0.f};

    const int t = threadIdx.x;
    const int lane = t & 63, w = t >> 6;
    const int wm = w >> 1, wn = w & 1;
    const int srow = t >> 2, scol = (t & 3) * 8;
    const int lm = lane & 15, lk = (lane >> 4) * 8;
    const int bm = blockIdx.y, bn = blockIdx.x;
    const u16* ap = ctx + (size_t)(bm * 128 + srow) * 1024 + scol;
    const u16* bp = wproj + (size_t)(bn * 128 + srow) * 1024 + scol;

    for (int k0 = 0; k0 < 1024; k0 += 32) {
        uint4 a0 = *(const uint4*)(ap + k0);
        uint4 a1 = *(const uint4*)(ap + (size_t)64 * 1024 + k0);
        uint4 b0 = *(const uint4*)(bp + k0);
        uint4 b1 = *(const uint4*)(bp + (size_t)64 * 1024 + k0);
        __syncthreads();
        *(uint4*)(As + srow * 32 + scol) = a0;
        *(uint4*)(As + (srow + 64) * 32 + scol) = a1;
        *(uint4*)(Bs + srow * 32 + scol) = b0;
        *(uint4*)(Bs + (srow + 64) * 32 + scol) = b1;
        __syncthreads();
        short8 af[4], bfr[4];
#pragma unroll
        for (int i = 0; i < 4; i++) {
            af[i]  = *(const short8*)(As + (wm * 64 + i * 16 + lm) * 32 + lk);
            bfr[i] = *(const short8*)(Bs + (wn * 64 + i * 16 + lm) * 32 + lk);
        }
#pragma unroll
        for (int mi = 0; mi < 4; mi++)
#pragma unroll
            for (int ni = 0; ni < 4; ni++)
                acc[mi][ni] = __builtin_amdgcn_mfma_f32_16x16x32_bf16(
                    af[mi], bfr[ni], acc[mi][ni], 0, 0, 0);
    }

    const int rbase = bm * 128 + wm * 64 + (lane >> 4) * 4;
    const int cbase = bn * 128 + wn * 64 + lm;
#pragma unroll
    for (int mi = 0; mi < 4; mi++)
#pragma unroll
        for (int ni = 0; ni < 4; ni++) {
            int col = cbase + ni * 16;
            float bias = bproj[col];
#pragma unroll
            for (int r = 0; r < 4; r++) {
                int row = rbase + mi * 16 + r;
                out[(size_t)row * 1024 + col] = acc[mi][ni][r] + bias;
            }
        }
}

// ---------------------------------------------------------------------------
extern "C" void kernel_launch(void* const* d_in, const int* in_sizes, int n_in,
                              void* d_out, int out_size, void* d_ws, size_t ws_size,
                              hipStream_t stream) {
    const float* x     = (const float*)d_in[0];
    const float* abias = (const float*)d_in[1];
    const float* wqkv  = (const float*)d_in[2];
    const float* qbias = (const float*)d_in[3];
    const float* vbias = (const float*)d_in[4];
    const float* wproj = (const float*)d_in[5];
    const float* bproj = (const float*)d_in[6];
    float* out = (float*)d_out;

    char* ws = (char*)d_ws;
    float*       qpre    = (float*)(ws + 0);
    float*       kpre    = (float*)(ws + 16777216);
    float*       vfq     = (float*)(ws + 33554432);
    u16*         wprojbf = (u16*)  (ws + 50331648);
    signed char* qint    = (signed char*)(ws + 52428800);
    int*         kT      = (int*)  (ws + 56623104);
    double*      qs      = (double*)(ws + 60817408);
    double*      ksT     = (double*)(ws + 61865984);
    double*      vs      = (double*)(ws + 62914560);
    float*       pmax    = (float*)(ws + 62947328);
    u16*         ctx     = (u16*)(ws + 0);          // alias qpre (dead after quant)

    cvt_bf16w<<<1024, 256, 0, stream>>>(wprojbf, wproj, 1048576);
    gemm_qkv3<<<dim3(24, 32), 256, 0, stream>>>(x, wqkv, qbias, vbias,
                                                qpre, kpre, vfq);
    quant_qk<<<512, 256, 0, stream>>>(qpre, qint, qs);
    quant_k<<<512, 256, 0, stream>>>(kpre, kT, ksT);
    vmax_part<<<dim3(16, 4), 256, 0, stream>>>(vfq, pmax);
    vmax_final<<<16, 256, 0, stream>>>(pmax, vs);
    vquant<<<4096, 256, 0, stream>>>(vfq, vs);
    attn<<<dim3(256, 16, 4), 256, 0, stream>>>(qint, kT, qs, ksT, vfq, abias, ctx);
    gemm_proj<<<dim3(8, 32), 256, 0, stream>>>(ctx, wprojbf, bproj, out);
}

// Round 10
// 531.479 us; speedup vs baseline: 1.2241x; 1.0990x over previous
//
#include <hip/hip_runtime.h>

// ---------------------------------------------------------------------------
// QuantSelfAttention on MI355X (gfx950).  B=4, L=1024, C=1024, H=16, D=64.
// Inputs f32, output f32.  Numerics (validated rounds 4-9, absmax 1.89e-3):
//   - qkv GEMM: fp16x2-split 3-pass MFMA + per-128-K-slab f64 accumulation
//   - q/k as int8 + per-32-group f64 scale; scores = exact int dots, f64 rescale
//   - softmax + round(a*255) in f64;  AV + proj GEMM post-cliff (f32/bf16)
// Round 10 (round 9: attn 294us @ VALUBusy 77% = VALU-issue bound; softmax
// f64 block ~640 inst/lane is the largest reducible term):
//   - attn: 1/sum reciprocal (16 divides -> 1 div + 16 mul; flip prob ~1e-5)
//   - attn: custom f64 exp (Cody-Waite + deg-10 Taylor + exponent bit-add,
//     rel err ~2e-13, exp(0)=1 exact; flip prob ~0.02 over all 67M elements)
//   - gemm_qkv3: N-split to 128x64 blocks (dacc 128->64 VGPR, LDS 32->24KB,
//     3 staging segments) -- per-output K-order unchanged = bit-identical
//   - vmax_part: 256 blocks (max is order-independent, exact)
//
// ws byte layout:
//   0         qpre   16MB f32   [aliased as ctx (bf16 8MB) after quant]
//   16777216  kpre   16MB f32
//   33554432  vfq    16MB f32
//   50331648  wprojbf 2MB u16
//   52428800  qint   4MB int8
//   56623104  kT     4MB int32 (64 bh x 16 j x 1024 m)
//   60817408  qs     1MB f64 (131072 groups)
//   61865984  ksT    1MB f64 (64 bh x 2 p x 1024 m)
//   62914560  vs     32KB f64 (4096)
//   62947328  pmax   1MB f32 (262144)   -> high-water 64.0MB (<67.3MB proven)
// ---------------------------------------------------------------------------

typedef unsigned short u16;
typedef unsigned int u32;
typedef __attribute__((ext_vector_type(8))) _Float16 half8;  // 8 f16 (4 VGPRs)
typedef __attribute__((ext_vector_type(4))) float f32x4;     // MFMA accumulator

__device__ __forceinline__ u16 f2b(float f) {   // f32 -> bf16 RNE
    u32 i;
    __builtin_memcpy(&i, &f, 4);
    return (u16)((i + 0x7FFFu + ((i >> 16) & 1u)) >> 16);
}

__device__ __forceinline__ void split16(float v, u16& hi, u16& lo) {
    _Float16 h = (_Float16)v;
    _Float16 l = (_Float16)(v - (float)h);
    __builtin_memcpy(&hi, &h, 2);
    __builtin_memcpy(&lo, &l, 2);
}

__device__ __forceinline__ int dot4(int a, int b, int c) {
#if __has_builtin(__builtin_amdgcn_sdot4)
    return __builtin_amdgcn_sdot4(a, b, c, false);
#else
    int r = c;
    r += ((a << 24) >> 24) * ((b << 24) >> 24);
    r += ((a << 16) >> 24) * ((b << 16) >> 24);
    r += ((a << 8) >> 24) * ((b << 8) >> 24);
    r += (a >> 24) * (b >> 24);
    return r;
#endif
}

// fast f64 exp for x <= 0 (scores are max-subtracted).  Cody-Waite range
// reduction + degree-10 Taylor (rel err ~2e-13) + exponent bit-add.
// exp(0) == 1.0 exactly.  x < -700 -> 0 (true value < 1e-304; a rounds to 0).
__device__ __forceinline__ double fexp(double x) {
    double kd = rint(x * 1.4426950408889634);
    double r = fma(kd, -6.93147180369123816490e-01, x);
    r = fma(kd, -1.90821492927058770002e-10, r);
    double p = 2.7557319223985888e-07;
    p = fma(p, r, 2.7557319223985890e-06);
    p = fma(p, r, 2.4801587301587302e-05);
    p = fma(p, r, 1.9841269841269841e-04);
    p = fma(p, r, 1.3888888888888889e-03);
    p = fma(p, r, 8.3333333333333333e-03);
    p = fma(p, r, 4.1666666666666664e-02);
    p = fma(p, r, 1.6666666666666666e-01);
    p = fma(p, r, 0.5);
    p = fma(p, r, 1.0);
    p = fma(p, r, 1.0);
    long long bits;
    __builtin_memcpy(&bits, &p, 8);
    bits += ((long long)kd) << 52;
    double e;
    __builtin_memcpy(&e, &bits, 8);
    return (x < -700.0) ? 0.0 : e;
}

// --- K0: w_proj f32 -> bf16 --------------------------------------------------
__global__ __launch_bounds__(256) void cvt_bf16w(u16* __restrict__ dst,
                                                 const float* __restrict__ src, int n) {
    int i = (blockIdx.x * 256 + threadIdx.x) * 4;
    if (i + 3 < n) {
        float4 v = *(const float4*)(src + i);
        ushort4 o;
        o.x = f2b(v.x); o.y = f2b(v.y); o.z = f2b(v.z); o.w = f2b(v.w);
        *(ushort4*)(dst + i) = o;
    }
}

// ---------------------------------------------------------------------------
// K1: qkv = x @ w_qkv^T + bias, fp16x2-split 3-pass MFMA, f64 slab accumulate.
// Round 10: 128x64 output blocks (grid 48 x 32).  Wave w: rows w*32..w*32+31,
// all 64 cols (2x4 frags of 16x16x32).  Per-output K-order identical to the
// round-4..9 passing versions -> bit-identical results.
// ---------------------------------------------------------------------------
__global__ __launch_bounds__(256) void gemm_qkv3(const float* __restrict__ A,
                                                 const float* __restrict__ Bm,
                                                 const float* __restrict__ qbias,
                                                 const float* __restrict__ vbias,
                                                 float* __restrict__ qws,
                                                 float* __restrict__ kws,
                                                 float* __restrict__ vws) {
    __shared__ u16 Ah[128 * 32], Al[128 * 32], Bh[64 * 32], Bl[64 * 32];
    const int t = threadIdx.x;
    const int lane = t & 63, w = t >> 6;
    const int srow = t >> 2, scol = (t & 3) * 8;
    const int lm = lane & 15, lk = (lane >> 4) * 8;
    const int bm = blockIdx.y, bn = blockIdx.x;

    const float* ap = A + (size_t)(bm * 128 + srow) * 1024 + scol;
    const float* bp = Bm + (size_t)(bn * 64 + srow) * 1024 + scol;

    double dacc[2][4][4];
#pragma unroll
    for (int i = 0; i < 2; i++)
#pragma unroll
        for (int j = 0; j < 4; j++)
#pragma unroll
            for (int r = 0; r < 4; r++) dacc[i][j][r] = 0.0;

    for (int slab = 0; slab < 8; slab++) {
        f32x4 acc[2][4];
#pragma unroll
        for (int i = 0; i < 2; i++)
#pragma unroll
            for (int j = 0; j < 4; j++) acc[i][j] = (f32x4){0.f, 0.f, 0.f, 0.f};

        for (int kc = 0; kc < 4; kc++) {
            const int k0 = slab * 128 + kc * 32;
            float vreg[3][8];
#pragma unroll
            for (int e = 0; e < 3; e++) {
                const float* src = (e < 2) ? (ap + e * (size_t)64 * 1024 + k0)
                                           : (bp + k0);
                float4 v0 = *(const float4*)(src);
                float4 v1 = *(const float4*)(src + 4);
                vreg[e][0] = v0.x; vreg[e][1] = v0.y; vreg[e][2] = v0.z; vreg[e][3] = v0.w;
                vreg[e][4] = v1.x; vreg[e][5] = v1.y; vreg[e][6] = v1.z; vreg[e][7] = v1.w;
            }
            __syncthreads();
#pragma unroll
            for (int e = 0; e < 3; e++) {
                union { u16 us[8]; uint4 v; } ph, pl;
#pragma unroll
                for (int j = 0; j < 8; j++) split16(vreg[e][j], ph.us[j], pl.us[j]);
                u16* dh = (e < 2) ? Ah : Bh;
                u16* dl = (e < 2) ? Al : Bl;
                int row = (e < 2) ? (srow + e * 64) : srow;
                *(uint4*)(dh + row * 32 + scol) = ph.v;
                *(uint4*)(dl + row * 32 + scol) = pl.v;
            }
            __syncthreads();

            half8 fah[2], fal[2], fbh[4], fbl[4];
#pragma unroll
            for (int i = 0; i < 2; i++) {
                int ra = (w * 32 + i * 16 + lm) * 32 + lk;
                fah[i] = *(const half8*)(Ah + ra);
                fal[i] = *(const half8*)(Al + ra);
            }
#pragma unroll
            for (int i = 0; i < 4; i++) {
                int rb = (i * 16 + lm) * 32 + lk;
                fbh[i] = *(const half8*)(Bh + rb);
                fbl[i] = *(const half8*)(Bl + rb);
            }
#pragma unroll
            for (int mi = 0; mi < 2; mi++)
#pragma unroll
                for (int ni = 0; ni < 4; ni++) {
                    acc[mi][ni] = __builtin_amdgcn_mfma_f32_16x16x32_f16(
                        fal[mi], fbh[ni], acc[mi][ni], 0, 0, 0);
                    acc[mi][ni] = __builtin_amdgcn_mfma_f32_16x16x32_f16(
                        fah[mi], fbl[ni], acc[mi][ni], 0, 0, 0);
                    acc[mi][ni] = __builtin_amdgcn_mfma_f32_16x16x32_f16(
                        fah[mi], fbh[ni], acc[mi][ni], 0, 0, 0);
                }
        }
#pragma unroll
        for (int i = 0; i < 2; i++)
#pragma unroll
            for (int j = 0; j < 4; j++)
#pragma unroll
                for (int r = 0; r < 4; r++) dacc[i][j][r] += (double)acc[i][j][r];
    }

    const int rbase = bm * 128 + w * 32 + (lane >> 4) * 4;
    const int cbase = bn * 64 + lm;
#pragma unroll
    for (int mi = 0; mi < 2; mi++)
#pragma unroll
        for (int ni = 0; ni < 4; ni++) {
            int col = cbase + ni * 16;
            int sel = col >> 10, cc = col & 1023;
            double bias = (sel == 0) ? (double)qbias[cc]
                        : ((sel == 2) ? (double)vbias[cc] : 0.0);
            float* dst = (sel == 0) ? qws : ((sel == 1) ? kws : vws);
#pragma unroll
            for (int r = 0; r < 4; r++) {
                int row = rbase + mi * 16 + r;
                dst[(size_t)row * 1024 + cc] = (float)(dacc[mi][ni][r] + bias);
            }
        }
}

// --- K2a: per-32-group quant of q -> int8 (row-major) + f64 scale ------------
__global__ __launch_bounds__(256) void quant_qk(const float* __restrict__ pre,
                                                signed char* __restrict__ qout,
                                                double* __restrict__ sout) {
    size_t g = (size_t)blockIdx.x * 256 + threadIdx.x;   // 131072 groups
    const float* p = pre + g * 32;
    float v[32];
    float amax = 0.f;
#pragma unroll
    for (int i = 0; i < 8; i++) {
        float4 q4 = ((const float4*)p)[i];
        v[i * 4 + 0] = q4.x; v[i * 4 + 1] = q4.y; v[i * 4 + 2] = q4.z; v[i * 4 + 3] = q4.w;
        amax = fmaxf(amax, fmaxf(fmaxf(fabsf(q4.x), fabsf(q4.y)),
                                 fmaxf(fabsf(q4.z), fabsf(q4.w))));
    }
    double s = fmax((double)amax / 127.0, 1e-8);
    sout[g] = s;
    int pk[8];
#pragma unroll
    for (int i = 0; i < 8; i++) {
        int b0 = (int)fmin(fmax(rint((double)v[i * 4 + 0] / s), -128.0), 127.0);
        int b1 = (int)fmin(fmax(rint((double)v[i * 4 + 1] / s), -128.0), 127.0);
        int b2 = (int)fmin(fmax(rint((double)v[i * 4 + 2] / s), -128.0), 127.0);
        int b3 = (int)fmin(fmax(rint((double)v[i * 4 + 3] / s), -128.0), 127.0);
        pk[i] = (b0 & 255) | ((b1 & 255) << 8) | ((b2 & 255) << 16) | ((b3 & 255) << 24);
    }
    int4* d = (int4*)(qout + g * 32);
    d[0] = make_int4(pk[0], pk[1], pk[2], pk[3]);
    d[1] = make_int4(pk[4], pk[5], pk[6], pk[7]);
}

// --- K2b: per-32-group quant of k -> TRANSPOSED j-major layout ---------------
__global__ __launch_bounds__(256) void quant_k(const float* __restrict__ pre,
                                               int* __restrict__ kT,
                                               double* __restrict__ ksT) {
    size_t g = (size_t)blockIdx.x * 256 + threadIdx.x;   // 131072 groups
    const float* p = pre + g * 32;
    float v[32];
    float amax = 0.f;
#pragma unroll
    for (int i = 0; i < 8; i++) {
        float4 q4 = ((const float4*)p)[i];
        v[i * 4 + 0] = q4.x; v[i * 4 + 1] = q4.y; v[i * 4 + 2] = q4.z; v[i * 4 + 3] = q4.w;
        amax = fmaxf(amax, fmaxf(fmaxf(fabsf(q4.x), fabsf(q4.y)),
                                 fmaxf(fabsf(q4.z), fabsf(q4.w))));
    }
    double s = fmax((double)amax / 127.0, 1e-8);
    int pk[8];
#pragma unroll
    for (int i = 0; i < 8; i++) {
        int b0 = (int)fmin(fmax(rint((double)v[i * 4 + 0] / s), -128.0), 127.0);
        int b1 = (int)fmin(fmax(rint((double)v[i * 4 + 1] / s), -128.0), 127.0);
        int b2 = (int)fmin(fmax(rint((double)v[i * 4 + 2] / s), -128.0), 127.0);
        int b3 = (int)fmin(fmax(rint((double)v[i * 4 + 3] / s), -128.0), 127.0);
        pk[i] = (b0 & 255) | ((b1 & 255) << 8) | ((b2 & 255) << 16) | ((b3 & 255) << 24);
    }
    const int m = (int)((g >> 5) & 1023);
    const int b = (int)(g >> 15);
    const int sub = (int)(g & 31);
    const int h = sub >> 1, pp = sub & 1;
    const int bh = b * 16 + h;
    int* dst = kT + ((size_t)bh * 16 + pp * 8) * 1024 + m;
#pragma unroll
    for (int i = 0; i < 8; i++) dst[i * 1024] = pk[i];
    ksT[((size_t)bh * 2 + pp) * 1024 + m] = s;
}

// --- K3a: partial max|v| over 16-row L-chunks (256 blocks) -------------------
__global__ __launch_bounds__(256) void vmax_part(const float* __restrict__ vws,
                                                 float* __restrict__ pmax) {
    const int lc = blockIdx.x, b = blockIdx.y, t = threadIdx.x;
#pragma unroll
    for (int j = 0; j < 4; j++) {
        int cc = t + j * 256;
        float mx = 0.f;
        for (int l = 0; l < 16; l++)
            mx = fmaxf(mx, fabsf(vws[((size_t)(b * 1024 + lc * 16 + l)) * 1024 + cc]));
        pmax[(size_t)(b * 64 + lc) * 1024 + cc] = mx;
    }
}

// --- K3b: reduce 64 partials -> vs[b*1024+cc] = max(amax/127, eps) f64 -------
__global__ __launch_bounds__(256) void vmax_final(const float* __restrict__ pmax,
                                                  double* __restrict__ vs) {
    int id = blockIdx.x * 256 + threadIdx.x;   // 4096
    int b = id >> 10, cc = id & 1023;
    float mx = 0.f;
    for (int p = 0; p < 64; p++)
        mx = fmaxf(mx, pmax[(size_t)(b * 64 + p) * 1024 + cc]);
    vs[id] = fmax((double)mx / 127.0, 1e-8);
}

// --- K3c: fake-quant v in place (f64 decisions, f32 store) -------------------
__global__ __launch_bounds__(256) void vquant(float* __restrict__ vws,
                                              const double* __restrict__ vs) {
    size_t e = ((size_t)blockIdx.x * 256 + threadIdx.x) * 4;
    int b = (int)(e >> 20), cc = (int)(e & 1023);
    float4 v = *(const float4*)(vws + e);
    double s0 = vs[b * 1024 + cc], s1 = vs[b * 1024 + cc + 1];
    double s2 = vs[b * 1024 + cc + 2], s3 = vs[b * 1024 + cc + 3];
    float4 o;
    o.x = (float)(fmin(fmax(rint((double)v.x / s0), -128.0), 127.0) * s0);
    o.y = (float)(fmin(fmax(rint((double)v.y / s1), -128.0), 127.0) * s1);
    o.z = (float)(fmin(fmax(rint((double)v.z / s2), -128.0), 127.0) * s2);
    o.w = (float)(fmin(fmax(rint((double)v.w / s3), -128.0), 127.0) * s3);
    *(float4*)(vws + e) = o;
}

// ---------------------------------------------------------------------------
// K4: attention, one wave per query row, LDS-staged k (conflict-free), fast
// f64 softmax (custom exp, single reciprocal).  Structure = round 9.
// ---------------------------------------------------------------------------
__global__ __launch_bounds__(256) void attn(const signed char* __restrict__ qint,
                                            const int* __restrict__ kT,
                                            const double* __restrict__ qs,
                                            const double* __restrict__ ksT,
                                            const float* __restrict__ vfq,
                                            const float* __restrict__ abias,
                                            u16* __restrict__ ctx) {
    __shared__ int    kTs[16][256];        // 16 KB
    __shared__ double ks0s[256], ks1s[256];//  4 KB
    __shared__ u32    packed[4][512];      //  8 KB: (n<<16)|m nonzero list
    const int t = threadIdx.x;
    const int wv = t >> 6, lane = t & 63;
    const int qt = blockIdx.x, h = blockIdx.y, b = blockIdx.z;
    const int row = qt * 4 + wv;
    const size_t qrow = (size_t)(b * 1024 + row);
    const int bh = b * 16 + h;

    const int* qv = (const int*)(qint + qrow * 1024 + h * 64);
    int qd[16];
#pragma unroll
    for (int j = 0; j < 4; j++) {
        int4 tmp = ((const int4*)qv)[j];
        qd[j * 4 + 0] = tmp.x; qd[j * 4 + 1] = tmp.y;
        qd[j * 4 + 2] = tmp.z; qd[j * 4 + 3] = tmp.w;
    }
    const double sq0 = qs[qrow * 32 + 2 * h], sq1 = qs[qrow * 32 + 2 * h + 1];
    const int* kTg = kT + (size_t)bh * 16384;
    const double* ks0g = ksT + (size_t)(bh * 2) * 1024;
    const double* ks1g = ksT + (size_t)(bh * 2 + 1) * 1024;
    const float* ab = abias + (size_t)row * 1024;

    double sd[16];
    for (int c = 0; c < 4; c++) {
        if (c) __syncthreads();
#pragma unroll
        for (int r = 0; r < 4; r++) {
            const int j = wv * 4 + r;
            int4 val = *(const int4*)(kTg + (size_t)j * 1024 + c * 256 + 4 * lane);
            *(int4*)(&kTs[j][4 * lane]) = val;
        }
        ks0s[t] = ks0g[c * 256 + t];
        ks1s[t] = ks1g[c * 256 + t];
        __syncthreads();
#pragma unroll
        for (int s = 0; s < 4; s++) {
            const int ml = s * 64 + lane;
            int I0 = 0, I1 = 0;
#pragma unroll
            for (int j = 0; j < 8; j++)  I0 = dot4(qd[j], kTs[j][ml], I0);
#pragma unroll
            for (int j = 8; j < 16; j++) I1 = dot4(qd[j], kTs[j][ml], I1);
            sd[c * 4 + s] = 0.125 * (sq0 * ks0s[ml] * (double)I0
                                   + sq1 * ks1s[ml] * (double)I1)
                          + (double)ab[c * 256 + ml];
        }
    }

    // softmax (f64): custom exp, single reciprocal
    double mx = sd[0];
#pragma unroll
    for (int it = 1; it < 16; it++) mx = fmax(mx, sd[it]);
#pragma unroll
    for (int off = 1; off < 64; off <<= 1) mx = fmax(mx, __shfl_xor(mx, off));
    double sum = 0.0;
#pragma unroll
    for (int it = 0; it < 16; it++) {
        double e = fexp(sd[it] - mx);
        sd[it] = e;
        sum += e;
    }
#pragma unroll
    for (int off = 1; off < 64; off <<= 1) sum += __shfl_xor(sum, off);
    const double inv = 1.0 / sum;

    // static quant + ballot compaction of nonzeros (ascending m)
    int base = 0;
#pragma unroll
    for (int it = 0; it < 16; it++) {
        double a = sd[it] * inv;
        double nd = fmin(fmax(rint(a * 255.0), 0.0), 255.0);
        int ni = (int)nd;
        unsigned long long mk = __ballot(ni != 0);
        if (ni != 0) {
            int pos = base + (int)__popcll(mk & ((1ull << lane) - 1ull));
            packed[wv][pos] = ((u32)ni << 16) | (u32)(it * 64 + lane);
        }
        base += (int)__popcll(mk);
    }
    __syncthreads();

    // AV: lane = head dim; iterate compacted list (wave-uniform trip count)
    float acc = 0.f;
    const float* vcol = vfq + ((size_t)b * 1024) * 1024 + h * 64 + lane;
    for (int j = 0; j < base; ++j) {
        u32 p = packed[wv][j];
        float a = (float)(p >> 16) / 255.0f;
        acc = fmaf(a, vcol[(size_t)(p & 1023u) * 1024], acc);
    }
    ctx[qrow * 1024 + h * 64 + lane] = f2b(acc);
}

// --- K5: out = ctx @ w_proj^T + b_proj, bf16 MFMA (post-cliff) ---------------
__global__ __launch_bounds__(256) void gemm_proj(const u16* __restrict__ ctx,
                                                 const u16* __restrict__ wproj,
                                                 const float* __restrict__ bproj,
                                                 float* __restrict__ out) {
    typedef __attribute__((ext_vector_type(8))) short short8;
    __shared__ u16 As[128 * 32], Bs[128 * 32];
    f32x4 acc[4][4];
#pragma unroll
    for (int i = 0; i < 4; i++)
#pragma unroll
        for (int j = 0; j < 4; j++) acc[i][j] = (f32x4){0.f, 0.f, 0.f, 0.f};

    const int t = threadIdx.x;
    const int lane = t & 63, w = t >> 6;
    const int wm = w >> 1, wn = w & 1;
    const int srow = t >> 2, scol = (t & 3) * 8;
    const int lm = lane & 15, lk = (lane >> 4) * 8;
    const int bm = blockIdx.y, bn = blockIdx.x;
    const u16* ap = ctx + (size_t)(bm * 128 + srow) * 1024 + scol;
    const u16* bp = wproj + (size_t)(bn * 128 + srow) * 1024 + scol;

    for (int k0 = 0; k0 < 1024; k0 += 32) {
        uint4 a0 = *(const uint4*)(ap + k0);
        uint4 a1 = *(const uint4*)(ap + (size_t)64 * 1024 + k0);
        uint4 b0 = *(const uint4*)(bp + k0);
        uint4 b1 = *(const uint4*)(bp + (size_t)64 * 1024 + k0);
        __syncthreads();
        *(uint4*)(As + srow * 32 + scol) = a0;
        *(uint4*)(As + (srow + 64) * 32 + scol) = a1;
        *(uint4*)(Bs + srow * 32 + scol) = b0;
        *(uint4*)(Bs + (srow + 64) * 32 + scol) = b1;
        __syncthreads();
        short8 af[4], bfr[4];
#pragma unroll
        for (int i = 0; i < 4; i++) {
            af[i]  = *(const short8*)(As + (wm * 64 + i * 16 + lm) * 32 + lk);
            bfr[i] = *(const short8*)(Bs + (wn * 64 + i * 16 + lm) * 32 + lk);
        }
#pragma unroll
        for (int mi = 0; mi < 4; mi++)
#pragma unroll
            for (int ni = 0; ni < 4; ni++)
                acc[mi][ni] = __builtin_amdgcn_mfma_f32_16x16x32_bf16(
                    af[mi], bfr[ni], acc[mi][ni], 0, 0, 0);
    }

    const int rbase = bm * 128 + wm * 64 + (lane >> 4) * 4;
    const int cbase = bn * 128 + wn * 64 + lm;
#pragma unroll
    for (int mi = 0; mi < 4; mi++)
#pragma unroll
        for (int ni = 0; ni < 4; ni++) {
            int col = cbase + ni * 16;
            float bias = bproj[col];
#pragma unroll
            for (int r = 0; r < 4; r++) {
                int row = rbase + mi * 16 + r;
                out[(size_t)row * 1024 + col] = acc[mi][ni][r] + bias;
            }
        }
}

// ---------------------------------------------------------------------------
extern "C" void kernel_launch(void* const* d_in, const int* in_sizes, int n_in,
                              void* d_out, int out_size, void* d_ws, size_t ws_size,
                              hipStream_t stream) {
    const float* x     = (const float*)d_in[0];
    const float* abias = (const float*)d_in[1];
    const float* wqkv  = (const float*)d_in[2];
    const float* qbias = (const float*)d_in[3];
    const float* vbias = (const float*)d_in[4];
    const float* wproj = (const float*)d_in[5];
    const float* bproj = (const float*)d_in[6];
    float* out = (float*)d_out;

    char* ws = (char*)d_ws;
    float*       qpre    = (float*)(ws + 0);
    float*       kpre    = (float*)(ws + 16777216);
    float*       vfq     = (float*)(ws + 33554432);
    u16*         wprojbf = (u16*)  (ws + 50331648);
    signed char* qint    = (signed char*)(ws + 52428800);
    int*         kT      = (int*)  (ws + 56623104);
    double*      qs      = (double*)(ws + 60817408);
    double*      ksT     = (double*)(ws + 61865984);
    double*      vs      = (double*)(ws + 62914560);
    float*       pmax    = (float*)(ws + 62947328);   // 1MB (262144 f32)
    u16*         ctx     = (u16*)(ws + 0);            // alias qpre

    cvt_bf16w<<<1024, 256, 0, stream>>>(wprojbf, wproj, 1048576);
    gemm_qkv3<<<dim3(48, 32), 256, 0, stream>>>(x, wqkv, qbias, vbias,
                                                qpre, kpre, vfq);
    quant_qk<<<512, 256, 0, stream>>>(qpre, qint, qs);
    quant_k<<<512, 256, 0, stream>>>(kpre, kT, ksT);
    vmax_part<<<dim3(64, 4), 256, 0, stream>>>(vfq, pmax);
    vmax_final<<<16, 256, 0, stream>>>(pmax, vs);
    vquant<<<4096, 256, 0, stream>>>(vfq, vs);
    attn<<<dim3(256, 16, 4), 256, 0, stream>>>(qint, kT, qs, ksT, vfq, abias, ctx);
    gemm_proj<<<dim3(8, 32), 256, 0, stream>>>(ctx, wprojbf, bproj, out);
}